// Round 1
// baseline (579.658 us; speedup 1.0000x reference)
//
#include <hip/hip_runtime.h>
#include <hip/hip_bf16.h>
#include <math.h>

// MoE top-2 SwiGLU, grouped-by-expert, bf16 MFMA.
// T=2048, H=1024, I=2048, E=16, K=2.
//
// Round 4: latency-bound fix (round-3: MfmaUtil 10%, 2 full-drain barriers/iter).
//   - software pipeline: LDS double-buffer + reg-prefetched B, raw s_barrier,
//     counted vmcnt (never 0 in loop). A staging is wave-private -> only B
//     needs the barrier -> ONE barrier per K-step.
//   - A-tile XOR swizzle (quad ^= (row>>1)&3) via pre-swizzled global source
//     for global_load_lds + swizzled read quad: 8-way bank conflict -> 2-way.
//   - s_setprio(1) around MFMA cluster.

#define T_TOK 2048
#define H_DIM 1024
#define I_DIM 2048
#define E_NUM 16
#define N_ASSIGN 4096
#define BM 128
#define TILE_MAX 48   // max sum of ceil(n_e/BM) = 4096/128 + 16

typedef __attribute__((ext_vector_type(8))) short short8;
typedef __attribute__((ext_vector_type(4))) float floatx4;

// ---------------- workspace layout (bytes) ----------------
#define WS_OFF_COUNTS   0
#define WS_OFF_OFFSETS  64                        // int[17]
#define WS_OFF_TOPKIDX  256                       // int[4096]
#define WS_OFF_TOPKW    (WS_OFF_TOPKIDX + 16384)  // float[4096]
#define WS_OFF_ROWTOK   (WS_OFF_TOPKW  + 16384)   // int[4096]
#define WS_OFF_ROWW     (WS_OFF_ROWTOK + 16384)   // float[4096]
#define WS_OFF_TILEE    (WS_OFF_ROWW   + 16384)   // int[64]
#define WS_OFF_TILEM    (WS_OFF_TILEE  + 256)     // int[64]
#define WS_OFF_TILEC    (WS_OFF_TILEM  + 256)     // int[1]
#define WS_OFF_XG       (128 * 1024)                      // bf16 [4096][1024]  8 MB
#define WS_OFF_H1       (WS_OFF_XG + 8u * 1024 * 1024)    // bf16 [4096][2048] 16 MB

// ---------------- bf16 helpers (RNE) ----------------
__device__ __forceinline__ ushort f2bf(float f) {
    union { float f; unsigned int u; } v; v.f = f;
    unsigned int r = (v.u + 0x7fffu + ((v.u >> 16) & 1u)) >> 16;
    return (ushort)r;
}

// ---------------- pipeline fences ----------------
#define FENCE_LGKM0() asm volatile("s_waitcnt lgkmcnt(0)" ::: "memory")
#define WAIT_VM(N)    asm volatile("s_waitcnt vmcnt(" #N ")" ::: "memory")
#define BARRIER_()                                    \
    do {                                              \
        FENCE_LGKM0();                                \
        __builtin_amdgcn_s_barrier();                 \
        asm volatile("" ::: "memory");                \
    } while (0)

// ---------------------------------------------------------------------------
// Kernel 1: router. One wave per token.
// ---------------------------------------------------------------------------
__global__ __launch_bounds__(64)
void router_kernel(const float* __restrict__ x,
                   const float* __restrict__ wr,
                   int* __restrict__ counts,
                   int* __restrict__ topk_idx,
                   float* __restrict__ topk_w) {
    const int t = blockIdx.x;
    const int lane = threadIdx.x;
    const float* xt = x + (size_t)t * H_DIM;

    float acc[E_NUM];
#pragma unroll
    for (int e = 0; e < E_NUM; e++) acc[e] = 0.f;

    for (int h = lane; h < H_DIM; h += 64) {
        const float xv = xt[h];
        const float* wrow = wr + h * E_NUM;
#pragma unroll
        for (int e = 0; e < E_NUM; e++) acc[e] += xv * wrow[e];
    }
#pragma unroll
    for (int off = 32; off > 0; off >>= 1) {
#pragma unroll
        for (int e = 0; e < E_NUM; e++)
            acc[e] += __shfl_down(acc[e], off);
    }
    if (lane == 0) {
        int e0 = 0; float l0 = acc[0];
        for (int e = 1; e < E_NUM; e++)
            if (acc[e] > l0) { l0 = acc[e]; e0 = e; }
        int e1 = (e0 == 0) ? 1 : 0;
        float l1 = acc[e1];
        for (int e = 0; e < E_NUM; e++)
            if (e != e0 && acc[e] > l1) { l1 = acc[e]; e1 = e; }
        const float w0 = 1.f / (1.f + __expf(l1 - l0));  // renorm == softmax over top-2
        const float w1 = 1.f - w0;
        topk_idx[t * 2 + 0] = e0;
        topk_idx[t * 2 + 1] = e1;
        topk_w[t * 2 + 0] = w0;
        topk_w[t * 2 + 1] = w1;
        atomicAdd(&counts[e0], 1);
        atomicAdd(&counts[e1], 1);
    }
}

// ---------------------------------------------------------------------------
// Kernel 2: bucket assignments by expert + build (expert, mtile) tile map.
// ---------------------------------------------------------------------------
__global__ __launch_bounds__(256)
void scatter_kernel(const int* __restrict__ counts,
                    int* __restrict__ offsets,
                    const int* __restrict__ topk_idx,
                    const float* __restrict__ topk_w,
                    int* __restrict__ row_token,
                    float* __restrict__ row_w,
                    int* __restrict__ tile_e,
                    int* __restrict__ tile_m,
                    int* __restrict__ tile_c) {
    __shared__ int base[E_NUM];
    __shared__ int fill[E_NUM];
    const int tid = threadIdx.x;
    if (tid == 0) {
        int run = 0, tc = 0;
        for (int e = 0; e < E_NUM; e++) {
            offsets[e] = run;
            base[e] = run;
            const int cnt = counts[e];
            run += cnt;
            for (int m = 0; m * BM < cnt; m++) {
                tile_e[tc] = e;
                tile_m[tc] = m;
                tc++;
            }
        }
        offsets[E_NUM] = run;
        *tile_c = tc;
    }
    if (tid < E_NUM) fill[tid] = 0;
    __syncthreads();
    for (int a = tid; a < N_ASSIGN; a += blockDim.x) {
        const int e = topk_idx[a];
        const int pos = atomicAdd(&fill[e], 1);
        const int dst = base[e] + pos;
        row_token[dst] = a >> 1;
        row_w[dst] = topk_w[a];
    }
}

// ---------------------------------------------------------------------------
// Kernel 3: gather x rows into expert-grouped bf16 matrix Xg[4096][1024].
// ---------------------------------------------------------------------------
__global__ __launch_bounds__(256)
void gather_x_kernel(const float* __restrict__ x,
                     const int* __restrict__ row_token,
                     ushort* __restrict__ Xg) {
    const int r = blockIdx.x;
    const int t = row_token[r];
    const int c = threadIdx.x;
    floatx4 v = ((const floatx4*)(x + (size_t)t * H_DIM))[c];
    ushort4 o;
    o.x = f2bf(v[0]); o.y = f2bf(v[1]); o.z = f2bf(v[2]); o.w = f2bf(v[3]);
    ((ushort4*)(Xg + (size_t)r * H_DIM))[c] = o;
}

// ---------------------------------------------------------------------------
// Kernel 4: fused gate+up grouped GEMM + SwiGLU epilogue -> h1 bf16.
// Pipelined: As/Bgs/Bus double-buffered; B reg-prefetch 1 sub-iter ahead;
// one raw barrier per BK=32 step; counted vmcnt (6 = B(4)+A(2) per sub-iter).
// A LDS is quad-swizzled (qs = q ^ ((row>>1)&3)) via pre-swizzled global src.
// ---------------------------------------------------------------------------
__global__ __launch_bounds__(256)
void gemm_gu_kernel(const ushort* __restrict__ Xg,
                    const float* __restrict__ wg,
                    const float* __restrict__ wu,
                    const int* __restrict__ offsets,
                    const float* __restrict__ row_w,
                    const int* __restrict__ tile_e,
                    const int* __restrict__ tile_m,
                    const int* __restrict__ tile_c,
                    ushort* __restrict__ h1) {
    if ((int)blockIdx.y >= *tile_c) return;
    const int e     = tile_e[blockIdx.y];
    const int mtile = tile_m[blockIdx.y];
    const int ntile = blockIdx.x;           // 0..31 (I/64)
    const int beg = offsets[e];
    const int n   = offsets[e + 1] - beg;

    __shared__ ushort As[2][BM * 32];       // row-major, swizzled quads
    __shared__ ushort Bgs[2][64 * 40];
    __shared__ ushort Bus[2][64 * 40];
    __shared__ float  wts[BM];

    const int tid  = threadIdx.x;
    const int lane = tid & 63;
    const int w    = tid >> 6;
    const int ml   = lane & 15;
    const int q    = lane >> 4;
    const int rq   = (ml >> 1) & 3;                    // reader quad XOR
    const int srcq = (lane & 3) ^ ((lane >> 3) & 3);   // staging source quad

    if (tid < BM) {
        const int rl = mtile * BM + tid;
        wts[tid] = (rl < n) ? row_w[beg + rl] : 0.f;
    }

    floatx4 accg[2][4], accu[2][4];
#pragma unroll
    for (int i = 0; i < 2; i++)
#pragma unroll
        for (int j = 0; j < 4; j++) {
            accg[i][j] = (floatx4){0.f, 0.f, 0.f, 0.f};
            accu[i][j] = (floatx4){0.f, 0.f, 0.f, 0.f};
        }

    // A staging: wave w, instr j covers rows 32w+16j..+16. Lane l -> physical
    // slot (row = +l>>2, qs = l&3); fetch global quad (l&3)^((l>>3)&3) so the
    // LDS holds the swizzled layout while gload_lds writes linearly.
    const ushort* Ap[2];
#pragma unroll
    for (int j = 0; j < 2; j++) {
        int row = beg + mtile * BM + 32 * w + 16 * j + (lane >> 2);
        row = row < 4095 ? row : 4095;
        Ap[j] = Xg + (size_t)row * H_DIM + srcq * 8;
    }

    const int kh = tid & 15;
    const int n4 = tid >> 4;
    const float* Bgp = wg + (size_t)e * H_DIM * I_DIM + ntile * 64 + n4 * 4;
    const float* Bup = wu + (size_t)e * H_DIM * I_DIM + ntile * 64 + n4 * 4;

    floatx4 g0p, g1p, u0p, u1p, g0q, g1q, u0q, u1q;

#define GU_ISSUE_A(k0v, buf)                                                   \
    {                                                                          \
        __builtin_amdgcn_global_load_lds(                                      \
            (const __attribute__((address_space(1))) unsigned int*)(Ap[0] + (k0v)), \
            (__attribute__((address_space(3))) unsigned int*)(&As[buf][(32 * w) * 32]), \
            16, 0, 0);                                                         \
        __builtin_amdgcn_global_load_lds(                                      \
            (const __attribute__((address_space(1))) unsigned int*)(Ap[1] + (k0v)), \
            (__attribute__((address_space(3))) unsigned int*)(&As[buf][(32 * w + 16) * 32]), \
            16, 0, 0);                                                         \
    }

#define GU_ISSUE_B(k0v, G0, G1, U0, U1)                                        \
    {                                                                          \
        const size_t boff = (size_t)((k0v) + 2 * kh) * I_DIM;                  \
        G0 = *(const floatx4*)(Bgp + boff);                                    \
        G1 = *(const floatx4*)(Bgp + boff + I_DIM);                            \
        U0 = *(const floatx4*)(Bup + boff);                                    \
        U1 = *(const floatx4*)(Bup + boff + I_DIM);                            \
    }

#define GU_CVT_B(buf, G0, G1, U0, U1)                                          \
    {                                                                          \
        _Pragma("unroll")                                                      \
        for (int j2 = 0; j2 < 4; j2++) {                                       \
            unsigned int pg = (unsigned int)f2bf(G0[j2]) |                     \
                              ((unsigned int)f2bf(G1[j2]) << 16);              \
            unsigned int pu = (unsigned int)f2bf(U0[j2]) |                     \
                              ((unsigned int)f2bf(U1[j2]) << 16);              \
            *(unsigned int*)&Bgs[buf][(n4 * 4 + j2) * 40 + 2 * kh] = pg;       \
            *(unsigned int*)&Bus[buf][(n4 * 4 + j2) * 40 + 2 * kh] = pu;       \
        }                                                                      \
    }

    // ---- prologue: stage k=0 (LDS) and k=32 (regs+LDS-A), outstanding = 6 ----
    GU_ISSUE_B(0, g0p, g1p, u0p, u1p);
    GU_ISSUE_A(0, 0);
    GU_ISSUE_B(32, g0q, g1q, u0q, u1q);
    GU_ISSUE_A(32, 1);
    WAIT_VM(6);                         // B(k=0) + A(k=0) complete
    GU_CVT_B(0, g0p, g1p, u0p, u1p);
    BARRIER_();

    // Sub-iter: read frags[cur]; fence; issue prefetch (6 vm); MFMA;
    // vmcnt(6) -> previous sub-iter's B regs + A stage complete; cvt -> nxt.
#define GU_STEP(cur, kpre, CG0, CG1, CU0, CU1, PG0, PG1, PU0, PU1)             \
    {                                                                          \
        short8 af[2], bgf[4], buf4[4];                                         \
        _Pragma("unroll")                                                      \
        for (int mt = 0; mt < 2; mt++)                                         \
            af[mt] = *(const short8*)&As[cur][(32 * w + mt * 16 + ml) * 32 +   \
                                              ((q ^ rq) * 8)];                 \
        FENCE_LGKM0();  /* af retired -> safe to re-stage As[cur] */           \
        GU_ISSUE_B(kpre, PG0, PG1, PU0, PU1);                                  \
        GU_ISSUE_A(kpre, cur);                                                 \
        _Pragma("unroll")                                                      \
        for (int nt = 0; nt < 4; nt++) {                                       \
            bgf[nt]  = *(const short8*)&Bgs[cur][(nt * 16 + ml) * 40 + q * 8]; \
            buf4[nt] = *(const short8*)&Bus[cur][(nt * 16 + ml) * 40 + q * 8]; \
        }                                                                      \
        __builtin_amdgcn_s_setprio(1);                                         \
        _Pragma("unroll")                                                      \
        for (int mt = 0; mt < 2; mt++)                                         \
            _Pragma("unroll")                                                  \
            for (int nt = 0; nt < 4; nt++) {                                   \
                accg[mt][nt] = __builtin_amdgcn_mfma_f32_16x16x32_bf16(        \
                    af[mt], bgf[nt], accg[mt][nt], 0, 0, 0);                   \
                accu[mt][nt] = __builtin_amdgcn_mfma_f32_16x16x32_bf16(        \
                    af[mt], buf4[nt], accu[mt][nt], 0, 0, 0);                  \
            }                                                                  \
        __builtin_amdgcn_s_setprio(0);                                         \
        WAIT_VM(6);                                                            \
        GU_CVT_B(cur ^ 1, CG0, CG1, CU0, CU1);                                 \
        BARRIER_();                                                            \
    }

    for (int k0 = 0; k0 < H_DIM; k0 += 64) {
        const int kpe = (k0 + 64) & (H_DIM - 1);   // wrap: last prefetches redundant
        const int kpo = (k0 + 96) & (H_DIM - 1);
        GU_STEP(0, kpe, g0q, g1q, u0q, u1q, g0p, g1p, u0p, u1p);
        GU_STEP(1, kpo, g0p, g1p, u0p, u1p, g0q, g1q, u0q, u1q);
    }
#undef GU_STEP
#undef GU_CVT_B
#undef GU_ISSUE_B
#undef GU_ISSUE_A

    // epilogue: h1 = bf16(silu(g)*u*w). C/D: col=ml, row=q*4+r within tile.
#pragma unroll
    for (int mt = 0; mt < 2; mt++)
#pragma unroll
        for (int r = 0; r < 4; r++) {
            const int rloc = 32 * w + mt * 16 + q * 4 + r;
            const int rl = mtile * BM + rloc;
            if (rl < n) {
                const float cw = wts[rloc];
#pragma unroll
                for (int nt = 0; nt < 4; nt++) {
                    const float g = accg[mt][nt][r];
                    const float s = g / (1.f + __expf(-g));
                    h1[(size_t)(beg + rl) * I_DIM + ntile * 64 + nt * 16 + ml] =
                        f2bf(s * accu[mt][nt][r] * cw);
                }
            }
        }
}

// ---------------------------------------------------------------------------
// Kernel 5: down grouped GEMM, split-K=2, atomicAdd partials into y (zeroed).
// Same pipeline as gemm_gu; 4 vm ops per sub-iter -> vmcnt(4).
// ---------------------------------------------------------------------------
__global__ __launch_bounds__(256)
void gemm_down_kernel(const ushort* __restrict__ h1,
                      const float* __restrict__ wd,
                      const int* __restrict__ offsets,
                      const int* __restrict__ row_token,
                      const int* __restrict__ tile_e,
                      const int* __restrict__ tile_m,
                      const int* __restrict__ tile_c,
                      float* __restrict__ y) {
    if ((int)blockIdx.y >= *tile_c) return;
    const int e     = tile_e[blockIdx.y];
    const int mtile = tile_m[blockIdx.y];
    const int ntile = blockIdx.x;           // 0..15 (H/64)
    const int kbase = blockIdx.z * 1024;    // split-K half
    const int beg = offsets[e];
    const int n   = offsets[e + 1] - beg;

    __shared__ ushort As[2][BM * 32];
    __shared__ ushort Bs[2][64 * 40];
    __shared__ int    toks[BM];

    const int tid  = threadIdx.x;
    const int lane = tid & 63;
    const int w    = tid >> 6;
    const int ml   = lane & 15;
    const int q    = lane >> 4;
    const int rq   = (ml >> 1) & 3;
    const int srcq = (lane & 3) ^ ((lane >> 3) & 3);

    if (tid < BM) {
        const int rl = mtile * BM + tid;
        toks[tid] = (rl < n) ? row_token[beg + rl] : 0;
    }

    floatx4 acc[2][4];
#pragma unroll
    for (int i = 0; i < 2; i++)
#pragma unroll
        for (int j = 0; j < 4; j++) acc[i][j] = (floatx4){0.f, 0.f, 0.f, 0.f};

    const ushort* Ap[2];
#pragma unroll
    for (int j = 0; j < 2; j++) {
        int row = beg + mtile * BM + 32 * w + 16 * j + (lane >> 2);
        row = row < 4095 ? row : 4095;
        Ap[j] = h1 + (size_t)row * I_DIM + kbase + srcq * 8;
    }

    const int kh = tid & 15;
    const int n4 = tid >> 4;
    const float* Bp = wd + (size_t)e * I_DIM * H_DIM +
                      (size_t)kbase * H_DIM + ntile * 64 + n4 * 4;

    floatx4 b0p, b1p, b0q, b1q;

#define D_ISSUE_A(k0v, buf)                                                    \
    {                                                                          \
        __builtin_amdgcn_global_load_lds(                                      \
            (const __attribute__((address_space(1))) unsigned int*)(Ap[0] + (k0v)), \
            (__attribute__((address_space(3))) unsigned int*)(&As[buf][(32 * w) * 32]), \
            16, 0, 0);                                                         \
        __builtin_amdgcn_global_load_lds(                                      \
            (const __attribute__((address_space(1))) unsigned int*)(Ap[1] + (k0v)), \
            (__attribute__((address_space(3))) unsigned int*)(&As[buf][(32 * w + 16) * 32]), \
            16, 0, 0);                                                         \
    }

#define D_ISSUE_B(k0v, B0, B1)                                                 \
    {                                                                          \
        const size_t boff = (size_t)((k0v) + 2 * kh) * H_DIM;                  \
        B0 = *(const floatx4*)(Bp + boff);                                     \
        B1 = *(const floatx4*)(Bp + boff + H_DIM);                             \
    }

#define D_CVT_B(buf, B0, B1)                                                   \
    {                                                                          \
        _Pragma("unroll")                                                      \
        for (int j2 = 0; j2 < 4; j2++) {                                       \
            unsigned int p = (unsigned int)f2bf(B0[j2]) |                      \
                             ((unsigned int)f2bf(B1[j2]) << 16);               \
            *(unsigned int*)&Bs[buf][(n4 * 4 + j2) * 40 + 2 * kh] = p;         \
        }                                                                      \
    }

    // ---- prologue ----
    D_ISSUE_B(0, b0p, b1p);
    D_ISSUE_A(0, 0);
    D_ISSUE_B(32, b0q, b1q);
    D_ISSUE_A(32, 1);
    WAIT_VM(4);                         // B(k=0) + A(k=0) complete
    D_CVT_B(0, b0p, b1p);
    BARRIER_();

#define D_STEP(cur, kpre, CB0, CB1, PB0, PB1)                                  \
    {                                                                          \
        short8 af[2], bfr[4];                                                  \
        _Pragma("unroll")                                                      \
        for (int mt = 0; mt < 2; mt++)                                         \
            af[mt] = *(const short8*)&As[cur][(32 * w + mt * 16 + ml) * 32 +   \
                                              ((q ^ rq) * 8)];                 \
        FENCE_LGKM0();                                                         \
        D_ISSUE_B(kpre, PB0, PB1);                                             \
        D_ISSUE_A(kpre, cur);                                                  \
        _Pragma("unroll")                                                      \
        for (int nt = 0; nt < 4; nt++)                                         \
            bfr[nt] = *(const short8*)&Bs[cur][(nt * 16 + ml) * 40 + q * 8];   \
        __builtin_amdgcn_s_setprio(1);                                         \
        _Pragma("unroll")                                                      \
        for (int mt = 0; mt < 2; mt++)                                         \
            _Pragma("unroll")                                                  \
            for (int nt = 0; nt < 4; nt++)                                     \
                acc[mt][nt] = __builtin_amdgcn_mfma_f32_16x16x32_bf16(         \
                    af[mt], bfr[nt], acc[mt][nt], 0, 0, 0);                    \
        __builtin_amdgcn_s_setprio(0);                                         \
        WAIT_VM(4);                                                            \
        D_CVT_B(cur ^ 1, CB0, CB1);                                            \
        BARRIER_();                                                            \
    }

    for (int k0 = 0; k0 < 1024; k0 += 64) {
        const int kpe = (k0 + 64) & 1023;
        const int kpo = (k0 + 96) & 1023;
        D_STEP(0, kpe, b0q, b1q, b0p, b1p);
        D_STEP(1, kpo, b0p, b1p, b0q, b1q);
    }
#undef D_STEP
#undef D_CVT_B
#undef D_ISSUE_B
#undef D_ISSUE_A

#pragma unroll
    for (int mt = 0; mt < 2; mt++)
#pragma unroll
        for (int r = 0; r < 4; r++) {
            const int rloc = 32 * w + mt * 16 + q * 4 + r;
            const int rl = mtile * BM + rloc;
            if (rl < n) {
                const int t = toks[rloc];
#pragma unroll
                for (int nt = 0; nt < 4; nt++)
                    atomicAdd(&y[(size_t)t * H_DIM + ntile * 64 + nt * 16 + ml],
                              acc[mt][nt][r]);
            }
        }
}

// ---------------------------------------------------------------------------
extern "C" void kernel_launch(void* const* d_in, const int* in_sizes, int n_in,
                              void* d_out, int out_size, void* d_ws, size_t ws_size,
                              hipStream_t stream) {
    const float* x  = (const float*)d_in[0];
    const float* wr = (const float*)d_in[1];
    const float* wg = (const float*)d_in[2];
    const float* wu = (const float*)d_in[3];
    const float* wd = (const float*)d_in[4];
    float* y = (float*)d_out;

    char* ws = (char*)d_ws;
    int*    counts    = (int*)(ws + WS_OFF_COUNTS);
    int*    offsets   = (int*)(ws + WS_OFF_OFFSETS);
    int*    topk_idx  = (int*)(ws + WS_OFF_TOPKIDX);
    float*  topk_w    = (float*)(ws + WS_OFF_TOPKW);
    int*    row_token = (int*)(ws + WS_OFF_ROWTOK);
    float*  row_w     = (float*)(ws + WS_OFF_ROWW);
    int*    tile_e    = (int*)(ws + WS_OFF_TILEE);
    int*    tile_m    = (int*)(ws + WS_OFF_TILEM);
    int*    tile_c    = (int*)(ws + WS_OFF_TILEC);
    ushort* Xg        = (ushort*)(ws + WS_OFF_XG);
    ushort* h1        = (ushort*)(ws + WS_OFF_H1);

    hipMemsetAsync(counts, 0, 64, stream);
    hipMemsetAsync(y, 0, (size_t)T_TOK * H_DIM * sizeof(float), stream);

    router_kernel<<<T_TOK, 64, 0, stream>>>(x, wr, counts, topk_idx, topk_w);
    scatter_kernel<<<1, 256, 0, stream>>>(counts, offsets, topk_idx, topk_w,
                                          row_token, row_w, tile_e, tile_m, tile_c);
    gather_x_kernel<<<N_ASSIGN, 256, 0, stream>>>(x, row_token, Xg);
    gemm_gu_kernel<<<dim3(I_DIM / 64, TILE_MAX), 256, 0, stream>>>(
        Xg, wg, wu, offsets, row_w, tile_e, tile_m, tile_c, h1);
    gemm_down_kernel<<<dim3(H_DIM / 64, TILE_MAX, 2), 256, 0, stream>>>(
        h1, wd, offsets, row_token, tile_e, tile_m, tile_c, y);
}